// Round 8
// baseline (715.898 us; speedup 1.0000x reference)
//
#include <hip/hip_runtime.h>
#include <hip/hip_bf16.h>

// QuantTokenPredictor: h (4,2048,256) f32, w (16384,256) f32 ->
// out (4,2048,16384) f32 Euclidean distances.
// sqrt(max(h2 - 2*h.w + w2, 0)) with the cross term via bf16 MFMA.
static constexpr int M_ = 8192;    // B*S
static constexpr int N_ = 16384;   // NUM_TOKS
static constexpr int K_ = 256;     // TOK_DIM
static constexpr int BM = 128, BN = 128;

typedef __attribute__((ext_vector_type(4))) float f32x4;
typedef __attribute__((ext_vector_type(8))) short bf16x8;

__device__ __forceinline__ ushort f2bf(float f) {
  __hip_bfloat16 b = __float2bfloat16(f);
  return __builtin_bit_cast(ushort, b);
}

// One wave per 256-element row: cast f32 -> bf16 and compute fp32 sum of squares.
__global__ __launch_bounds__(256) void cast_rows_k(
    const float* __restrict__ in, ushort* __restrict__ outb,
    float* __restrict__ sq)
{
  const int row  = blockIdx.x * 4 + (threadIdx.x >> 6);
  const int lane = threadIdx.x & 63;
  const float4 v = reinterpret_cast<const float4*>(in)[(size_t)row * 64 + lane];
  ushort4 o;
  o.x = f2bf(v.x); o.y = f2bf(v.y); o.z = f2bf(v.z); o.w = f2bf(v.w);
  reinterpret_cast<ushort4*>(outb)[(size_t)row * 64 + lane] = o;
  float s = v.x * v.x + v.y * v.y + v.z * v.z + v.w * v.w;
  #pragma unroll
  for (int off = 32; off > 0; off >>= 1) s += __shfl_down(s, off, 64);
  if (lane == 0) sq[row] = s;
}

// No-LDS, no-barrier GEMM: A+B are L2/L3-resident (12 MB total), so MFMA
// fragments are loaded straight from global (L1/L2 hits). 128x128 block,
// 4 independent waves of 64x64, K=256 fully unrolled with a 2-deep
// register double-buffer. Zero __syncthreads -> no vmcnt(0) drains.
__global__ __launch_bounds__(256) void dist_gemm_k(
    const ushort* __restrict__ A,    // M x K bf16 (h)
    const ushort* __restrict__ Bm,   // N x K bf16 (w)
    const float* __restrict__ h2,    // M
    const float* __restrict__ w2,    // N
    float* __restrict__ C)           // M x N f32
{
  const int lane = threadIdx.x & 63;
  const int wid  = threadIdx.x >> 6;

  // XCD-aware swizzle; grid = 8192 (divisible by 8) -> bijective.
  const int nwg = gridDim.x;
  const int cpx = nwg >> 3;
  const int bid = (blockIdx.x & 7) * cpx + (blockIdx.x >> 3);

  const int nbn  = N_ / BN;          // 128
  const int brow = (bid / nbn) * BM;
  const int bcol = (bid % nbn) * BN;

  const int wrow = (wid >> 1) * 64;
  const int wcol = (wid & 1) * 64;

  // Fragment addressing (identical lane->element map as the verified LDS
  // version): row = tileRow + i*16 + (lane&15), k = kk*32 + (lane>>4)*8.
  const int rl = lane & 15;
  const int kq = (lane >> 4) * 8;
  const ushort* Ab = A  + (size_t)(brow + wrow + rl) * K_ + kq;
  const ushort* Bb = Bm + (size_t)(bcol + wcol + rl) * K_ + kq;

  f32x4 acc[4][4] = {};
  bf16x8 a0[4], b0[4], a1[4], b1[4];

  #pragma unroll
  for (int i = 0; i < 4; ++i) {
    a0[i] = *reinterpret_cast<const bf16x8*>(Ab + (size_t)i * 16 * K_);
    b0[i] = *reinterpret_cast<const bf16x8*>(Bb + (size_t)i * 16 * K_);
  }

  #pragma unroll
  for (int kk = 0; kk < 8; ++kk) {             // fully unrolled: kk&1 static
    const bf16x8* ac = (kk & 1) ? a1 : a0;
    const bf16x8* bc = (kk & 1) ? b1 : b0;
    bf16x8* an = (kk & 1) ? a0 : a1;
    bf16x8* bn = (kk & 1) ? b0 : b1;
    if (kk < 7) {
      const int ko = (kk + 1) * 32;            // next k-step (ushort offset)
      #pragma unroll
      for (int i = 0; i < 4; ++i) {
        an[i] = *reinterpret_cast<const bf16x8*>(Ab + (size_t)i * 16 * K_ + ko);
        bn[i] = *reinterpret_cast<const bf16x8*>(Bb + (size_t)i * 16 * K_ + ko);
      }
    }
    #pragma unroll
    for (int i = 0; i < 4; ++i)
      #pragma unroll
      for (int j = 0; j < 4; ++j)
        acc[i][j] = __builtin_amdgcn_mfma_f32_16x16x32_bf16(
            ac[i], bc[j], acc[i][j], 0, 0, 0);
  }

  // Epilogue: C/D layout col = lane&15, row = (lane>>4)*4 + reg  [m89/m91].
  // Non-temporal stores: 537 MB streams out once, keep it out of L2 so B
  // panels stay resident.
  const int cl   = lane & 15;
  const int row0 = brow + wrow + ((lane >> 4) << 2);
  const int col0 = bcol + wcol;
  float h2v[16];
  #pragma unroll
  for (int i = 0; i < 4; ++i)
    #pragma unroll
    for (int r = 0; r < 4; ++r)
      h2v[i * 4 + r] = h2[row0 + i * 16 + r];

  #pragma unroll
  for (int j = 0; j < 4; ++j) {
    const int col  = col0 + j * 16 + cl;
    const float wc = w2[col];
    #pragma unroll
    for (int i = 0; i < 4; ++i) {
      const int row = row0 + i * 16;
      #pragma unroll
      for (int r = 0; r < 4; ++r) {
        const float v = h2v[i * 4 + r] - 2.0f * acc[i][j][r] + wc;
        __builtin_nontemporal_store(sqrtf(fmaxf(v, 0.0f)),
                                    &C[(size_t)(row + r) * N_ + col]);
      }
    }
  }
}

// Safety-net fallback if workspace is too small (pure fp32, slow but correct).
__global__ void naive_dist_k(const float* __restrict__ h,
                             const float* __restrict__ w,
                             float* __restrict__ C)
{
  const size_t idx = (size_t)blockIdx.x * 256 + threadIdx.x;
  const int m = (int)(idx / N_);
  const int n = (int)(idx % N_);
  const float* hr = h + (size_t)m * K_;
  const float* wr = w + (size_t)n * K_;
  float dot = 0.f, hh = 0.f, ww = 0.f;
  for (int k = 0; k < K_; ++k) {
    const float a = hr[k], b = wr[k];
    dot += a * b; hh += a * a; ww += b * b;
  }
  C[idx] = sqrtf(fmaxf(hh - 2.0f * dot + ww, 0.0f));
}

extern "C" void kernel_launch(void* const* d_in, const int* in_sizes, int n_in,
                              void* d_out, int out_size, void* d_ws, size_t ws_size,
                              hipStream_t stream) {
  const float* h = (const float*)d_in[0];
  const float* w = (const float*)d_in[1];
  float* out = (float*)d_out;

  const size_t need = (size_t)M_ * K_ * 2 + (size_t)N_ * K_ * 2
                    + (size_t)M_ * 4 + (size_t)N_ * 4;
  if (ws_size < need) {
    naive_dist_k<<<(int)(((size_t)M_ * N_) / 256), 256, 0, stream>>>(h, w, out);
    return;
  }

  ushort* hb = (ushort*)d_ws;
  ushort* wb = hb + (size_t)M_ * K_;
  float*  s1 = (float*)(wb + (size_t)N_ * K_);   // h2: M floats
  float*  s2 = s1 + M_;                          // w2: N floats

  cast_rows_k<<<M_ / 4, 256, 0, stream>>>(h, hb, s1);
  cast_rows_k<<<N_ / 4, 256, 0, stream>>>(w, wb, s2);
  dist_gemm_k<<<(M_ / BM) * (N_ / BN), 256, 0, stream>>>(hb, wb, s1, s2, out);
}